// Round 4
// baseline (3236.653 us; speedup 1.0000x reference)
//
#include <hip/hip_runtime.h>
#include <stdint.h>

// ---------------------------------------------------------------------------
// Seq2Seq (VGG-feature encoder biGRU + const-attention + 2-layer GRU decoder)
// B=32, S=512, C=512, EH=256, DH=256, T=128, V=512, E=128
//
// Attention scores = enc*w_enc + h2*w_h + b; the h2 term is constant over the
// softmax axis -> attention weights / context are the SAME for every decode
// step. Decoder == 2-layer GRU with constant extra input.
//
// Precision design: f16 operands for ALL matmuls (11-bit mantissa).
// Accumulation f32 (MFMA native), activations f32, gi2/emb_all/ctxp f32.
//
// R3 fix: k_bias used `i & 767` as mod-768 — 767 has bit 8 CLEAR, so z-gate
// (fwd) and all backward biases were scrambled -> absmax 0.52 in both bf16
// and f16 (precision-independent, which is what exposed it).
// ---------------------------------------------------------------------------

typedef unsigned short u16;
typedef _Float16 h16;
typedef _Float16 f16x8 __attribute__((ext_vector_type(8)));
typedef float    f32x4 __attribute__((ext_vector_type(4)));

__device__ __forceinline__ f16x8 ld8(const h16* p){ return *reinterpret_cast<const f16x8*>(p); }
// MFMA 16x16x32 f16.  A: lane l, elem i -> A[m=l&15][k=8*(l>>4)+i]
//                     D: lane l, reg  r -> D[m=4*(l>>4)+r][n=l&15]
__device__ __forceinline__ f32x4 mfma16(f16x8 a, f16x8 b, f32x4 c){
  return __builtin_amdgcn_mfma_f32_16x16x32_f16(a, b, c, 0, 0, 0);
}
__device__ __forceinline__ float sigm(float x){ return 1.f/(1.f + __expf(-x)); }
__device__ __forceinline__ float tanhx(float x){ float e = __expf(2.f*x); return 1.f - 2.f/(e+1.f); }

__device__ __forceinline__ void gl_lds16(const void* g, void* l){
  __builtin_amdgcn_global_load_lds(
      (const __attribute__((address_space(1))) uint32_t*)g,
      (__attribute__((address_space(3))) uint32_t*)l, 16, 0, 0);
}

__device__ __forceinline__ void waitflag(int* f){
  while (__hip_atomic_load(f, __ATOMIC_RELAXED, __HIP_MEMORY_SCOPE_AGENT) == 0)
    __builtin_amdgcn_s_sleep(2);
  __builtin_amdgcn_fence(__ATOMIC_ACQUIRE, "agent");
}
__device__ __forceinline__ void post_flag(int* f, int tid){
  __builtin_amdgcn_fence(__ATOMIC_RELEASE, "agent");
  __syncthreads();
  if (tid == 0) __hip_atomic_store(f, 1, __ATOMIC_RELAXED, __HIP_MEMORY_SCOPE_AGENT);
}

// -------------------------------- transpose --------------------------------
// source [32][512][512] f32 (b, c, s)  ->  Xt f16 [s*32+b][c]
__global__ __launch_bounds__(256) void k_transpose(const float* __restrict__ src,
                                                   h16* __restrict__ Xt){
  __shared__ h16 t[64][65];
  int blk = blockIdx.x;
  int b = blk >> 6, ct = (blk >> 3) & 7, st = blk & 7;
  int c0 = ct*64, s0 = st*64;
  int jj = threadIdx.x & 63, ii0 = threadIdx.x >> 6;   // ii0: 0..3
  for (int q = 0; q < 16; ++q){
    int i = ii0 + q*4;                                  // c-local
    t[i][jj] = (h16)src[((size_t)(b*512 + c0 + i))*512 + s0 + jj];
  }
  __syncthreads();
  for (int q = 0; q < 16; ++q){
    int srow = ii0 + q*4;                               // s-local
    Xt[((size_t)((s0+srow)*32 + b))*512 + c0 + jj] = t[jj][srow];
  }
}

// --------------------------------- casts -----------------------------------
struct CastSegs {
  const float* src[11];
  h16* dst[11];
  int sstride[11];
  int lgr[11];          // log2(row length)
  int startblk[12];
};
__global__ __launch_bounds__(256) void k_cast(CastSegs cs){
  int blk = blockIdx.x;
  int seg = 0;
  while (seg < 10 && blk >= cs.startblk[seg+1]) ++seg;
  int base = (blk - cs.startblk[seg])*2048 + threadIdx.x*8;
  int lgr = cs.lgr[seg];
  int row = base >> lgr, col = base & ((1<<lgr)-1);
  const float* sp = cs.src[seg] + (size_t)row*cs.sstride[seg] + col;
  float4 v0 = reinterpret_cast<const float4*>(sp)[0];
  float4 v1 = reinterpret_cast<const float4*>(sp)[1];
  union { h16 o[8]; uint4 u; } pk;
  pk.o[0]=(h16)v0.x; pk.o[1]=(h16)v0.y; pk.o[2]=(h16)v0.z; pk.o[3]=(h16)v0.w;
  pk.o[4]=(h16)v1.x; pk.o[5]=(h16)v1.y; pk.o[6]=(h16)v1.z; pk.o[7]=(h16)v1.w;
  *reinterpret_cast<uint4*>(cs.dst[seg] + base) = pk.u;
}

// fold bih + bhh(r,z) into per-gate bias vectors (n-gate bhh stays separate)
__global__ __launch_bounds__(256) void k_bias(
    const float* eBihF, const float* eBhhF, const float* eBihB, const float* eBhhB,
    const float* d0bih, const float* d0bhh, const float* d1bih, const float* d1bhh,
    float* enc_bias, float* d0bias, float* d1bias){
  int tid = threadIdx.x;
  for (int i = tid; i < 1536; i += 256){
    bool bwd = i >= 768;
    int u = bwd ? i - 768 : i;      // R3 fix: was `i & 767` (767 lacks bit 8!)
    float v = (bwd ? eBihB : eBihF)[u] + (u < 512 ? (bwd ? eBhhB : eBhhF)[u] : 0.f);
    enc_bias[i] = v;
  }
  for (int i = tid; i < 768; i += 256){
    d0bias[i] = d0bih[i] + (i < 512 ? d0bhh[i] : 0.f);
    d1bias[i] = d1bih[i] + (i < 512 ? d1bhh[i] : 0.f);
  }
}

// --------------------------------- GEMM ------------------------------------
// C[m,n] = sum_k A[m,k]*B[n,k] (+bias[n]).  A,B f16 row-major. Tile 128x64,
// BK=64, 4 waves (2x2), per wave 64x32 (4x2 16x16 tiles).
struct GemmP {
  const h16* A; const h16* B; const float* bias;
  float* Cf; h16* Ch; float* Crm;   // exactly one non-null
  int M, N, K, lda, ldb;
};
__global__ __launch_bounds__(256) void k_gemm(GemmP g){
  __shared__ __align__(16) h16 As[128*72];
  __shared__ __align__(16) h16 Bs[64*72];
  int tid = threadIdx.x, lane = tid & 63, wid = tid >> 6;
  int l15 = lane & 15, lg = lane >> 4;
  int m0 = blockIdx.y*128, n0 = blockIdx.x*64;
  int wm = wid & 1, wn = wid >> 1;
  f32x4 acc[4][2];
  for (int mt=0; mt<4; ++mt) for (int nt=0; nt<2; ++nt){ f32x4 z = {0.f,0.f,0.f,0.f}; acc[mt][nt] = z; }
  for (int k0 = 0; k0 < g.K; k0 += 64){
    for (int it = 0; it < 4; ++it){
      int c = tid + it*256; int row = c >> 3, kc = (c & 7)*8;
      uint4 v = {0,0,0,0};
      if (m0 + row < g.M) v = *reinterpret_cast<const uint4*>(g.A + (size_t)(m0+row)*g.lda + k0 + kc);
      *reinterpret_cast<uint4*>(&As[row*72 + kc]) = v;
    }
    for (int it = 0; it < 2; ++it){
      int c = tid + it*256; int row = c >> 3, kc = (c & 7)*8;
      uint4 v = *reinterpret_cast<const uint4*>(g.B + (size_t)(n0+row)*g.ldb + k0 + kc);
      *reinterpret_cast<uint4*>(&Bs[row*72 + kc]) = v;
    }
    __syncthreads();
    for (int kk = 0; kk < 2; ++kk){
      f16x8 a[4], bb[2];
      for (int mt=0; mt<4; ++mt) a[mt]  = ld8(&As[(wm*64 + mt*16 + l15)*72 + kk*32 + lg*8]);
      for (int nt=0; nt<2; ++nt) bb[nt] = ld8(&Bs[(wn*32 + nt*16 + l15)*72 + kk*32 + lg*8]);
      for (int mt=0; mt<4; ++mt) for (int nt=0; nt<2; ++nt)
        acc[mt][nt] = mfma16(a[mt], bb[nt], acc[mt][nt]);
    }
    __syncthreads();
  }
  for (int mt=0; mt<4; ++mt) for (int nt=0; nt<2; ++nt) for (int r=0; r<4; ++r){
    int m = m0 + wm*64 + mt*16 + 4*lg + r;
    int n = n0 + wn*32 + nt*16 + l15;
    if (m < g.M){
      float v = acc[mt][nt][r] + (g.bias ? g.bias[n] : 0.f);
      if (g.Cf) g.Cf[(size_t)m*g.N + n] = v;
      if (g.Ch) g.Ch[(size_t)m*g.N + n] = (h16)v;
      if (g.Crm) g.Crm[(size_t)(m & 31)*65536 + (size_t)(m >> 5)*512 + n] = v;  // [B][T][V]
    }
  }
}

// ------------------------------ encoder RNN --------------------------------
// 4 WGs: blockIdx = dir*2 + half. Each WG: 16 batch rows, full 768-row GRU.
// 8 waves; wave w owns h-units [32w,32w+32) across all 3 gates; Whh slice
// resident in VGPRs (48 frags = 192 VGPR). h via LDS (f16, dbuf); gi
// prefetched one step ahead via global_load_lds (linear layout).
#define HSP 264
__global__ __launch_bounds__(512, 2) void k_enc_rnn(
    const h16* __restrict__ WhhF, const h16* __restrict__ WhhB,
    const float* __restrict__ bhhF, const float* __restrict__ bhhB,
    const h16* __restrict__ gi_enc,   // [16384][1536] f16
    h16* __restrict__ enc)            // [32][512][512] f16
{
  const int tid = threadIdx.x, lane = tid & 63, wid = tid >> 6;
  const int l15 = lane & 15, lg = lane >> 4;
  const int dir = blockIdx.x >> 1, half = blockIdx.x & 1, boff = half*16;
  const int j0 = wid*32;
  const h16* W = dir ? WhhB : WhhF;
  const float* bhh = dir ? bhhB : bhhF;

  __shared__ __align__(16) h16 hs[2][16*HSP];
  __shared__ __align__(16) h16 gis[2][16*768];

  f16x8 bw[3][2][8];
  #pragma unroll
  for (int gg=0; gg<3; ++gg) for (int jt=0; jt<2; ++jt) for (int kk=0; kk<8; ++kk)
    bw[gg][jt][kk] = ld8(W + (size_t)(gg*256 + j0 + jt*16 + l15)*256 + kk*32 + lg*8);
  float bhn[2] = { bhh[512 + j0 + l15], bhh[512 + j0 + 16 + l15] };
  float h_own[2][4] = {{0,0,0,0},{0,0,0,0}};
  for (int i = tid; i < 16*HSP; i += 512) hs[0][i] = (h16)0.f;
  { // prefetch gi for p=0
    int s0 = dir ? 511 : 0;
    const h16* gb = gi_enc + (size_t)(s0*32 + boff)*1536 + dir*768;
    for (int q = 0; q < 3; ++q){
      int c = q*512 + tid;
      int row = c/96, col = (c%96)*8;
      gl_lds16(gb + (size_t)row*1536 + col, &gis[0][c*8]);
    }
  }
  __syncthreads();

  for (int p = 0; p < 512; ++p){
    const int cur = p & 1, nxt = cur ^ 1;
    const int s = dir ? (511 - p) : p;
    { // prefetch gi for p+1
      int p2 = (p+1 < 512) ? p+1 : p;
      int s2 = dir ? (511 - p2) : p2;
      const h16* gb = gi_enc + (size_t)(s2*32 + boff)*1536 + dir*768;
      for (int q = 0; q < 3; ++q){
        int c = q*512 + tid;
        int row = c/96, col = (c%96)*8;
        gl_lds16(gb + (size_t)row*1536 + col, &gis[nxt][c*8]);
      }
    }
    f32x4 acc[3][2];
    #pragma unroll
    for (int jt=0; jt<2; ++jt)
      #pragma unroll
      for (int r=0; r<4; ++r){
        int b = 4*lg + r, u = j0 + jt*16 + l15;
        acc[0][jt][r] = (float)gis[cur][b*768 + u];
        acc[1][jt][r] = (float)gis[cur][b*768 + 256 + u];
        acc[2][jt][r] = jt ? bhn[1] : bhn[0];
      }
    f16x8 af[4];
    #pragma unroll
    for (int kk=0; kk<4; ++kk) af[kk] = ld8(&hs[cur][l15*HSP + kk*32 + lg*8]);
    #pragma unroll
    for (int kk=0; kk<4; ++kk)
      for (int gg=0; gg<3; ++gg) for (int jt=0; jt<2; ++jt)
        acc[gg][jt] = mfma16(af[kk], bw[gg][jt][kk], acc[gg][jt]);
    #pragma unroll
    for (int kk=0; kk<4; ++kk) af[kk] = ld8(&hs[cur][l15*HSP + (kk+4)*32 + lg*8]);
    #pragma unroll
    for (int kk=0; kk<4; ++kk)
      for (int gg=0; gg<3; ++gg) for (int jt=0; jt<2; ++jt)
        acc[gg][jt] = mfma16(af[kk], bw[gg][jt][kk+4], acc[gg][jt]);
    #pragma unroll
    for (int jt=0; jt<2; ++jt)
      for (int r=0; r<4; ++r){
        int b = 4*lg + r, j = j0 + jt*16 + l15;
        float gn = (float)gis[cur][b*768 + 512 + j];
        float rr = sigm(acc[0][jt][r]);
        float zz = sigm(acc[1][jt][r]);
        float nn = tanhx(gn + rr*acc[2][jt][r]);
        float hv = (1.f - zz)*nn + zz*h_own[jt][r];
        h_own[jt][r] = hv;
        h16 hb = (h16)hv;
        enc[((size_t)(boff + b)*512 + s)*512 + dir*256 + j] = hb;
        hs[nxt][b*HSP + j] = hb;
      }
    __syncthreads();
  }
}

// ------------------------------- attention ---------------------------------
__global__ __launch_bounds__(256) void k_attn(const h16* __restrict__ enc,
                                              const float* __restrict__ attW,
                                              h16* __restrict__ ctx_h){
  int b = blockIdx.x, tid = threadIdx.x;
  __shared__ float sc[512];
  __shared__ float red[8];
  const h16* eb = enc + (size_t)b*512*512;
  for (int sidx = tid; sidx < 512; sidx += 256){
    const h16* row = eb + (size_t)sidx*512;
    float acc = 0.f;
    for (int i = 0; i < 512; i += 4){
      acc += (float)row[i]*attW[i] + (float)row[i+1]*attW[i+1]
           + (float)row[i+2]*attW[i+2] + (float)row[i+3]*attW[i+3];
    }
    sc[sidx] = acc;
  }
  __syncthreads();
  float m = -1e30f;
  for (int i = tid; i < 512; i += 256) m = fmaxf(m, sc[i]);
  for (int off = 32; off > 0; off >>= 1) m = fmaxf(m, __shfl_down(m, off, 64));
  if (!(tid & 63)) red[tid >> 6] = m;
  __syncthreads();
  m = fmaxf(fmaxf(red[0], red[1]), fmaxf(red[2], red[3]));
  float sum = 0.f;
  for (int i = tid; i < 512; i += 256){ float e = __expf(sc[i] - m); sc[i] = e; sum += e; }
  for (int off = 32; off > 0; off >>= 1) sum += __shfl_down(sum, off, 64);
  if (!(tid & 63)) red[4 + (tid >> 6)] = sum;
  __syncthreads();
  float inv = 1.f / (red[4] + red[5] + red[6] + red[7]);
  float a0 = 0.f, a1 = 0.f;
  for (int s2 = 0; s2 < 512; ++s2){
    float w = sc[s2]*inv;
    a0 += w * (float)eb[(size_t)s2*512 + tid];
    a1 += w * (float)eb[(size_t)s2*512 + tid + 256];
  }
  ctx_h[b*512 + tid]       = (h16)a0;
  ctx_h[b*512 + tid + 256] = (h16)a1;
}

// ------------------------------ decoder RNN --------------------------------
// 6 WGs: blockIdx = kind*2 + p  (kind 0=A: h1-GRU, 1=C: gi2 GEMM, 2=B: h2-GRU)
__global__ __launch_bounds__(512, 2) void k_dec_rnn(
    const h16* __restrict__ Whh0, const h16* __restrict__ Wih1, const h16* __restrict__ Whh1,
    const float* __restrict__ bhh0, const float* __restrict__ d1bias, const float* __restrict__ bhh1,
    const float* __restrict__ emb_all,   // [512][768]  (includes d0bias)
    const float* __restrict__ ctxp,      // [32][768]
    const int* __restrict__ target,      // [32][128]
    h16* __restrict__ h1n, float* __restrict__ gi2, h16* __restrict__ h2a,
    int* __restrict__ flagA, int* __restrict__ flagC)
{
  const int tid = threadIdx.x, lane = tid & 63, wid = tid >> 6;
  const int l15 = lane & 15, lg = lane >> 4;
  const int p = blockIdx.x & 1, kind = blockIdx.x >> 1;
  const int bg0 = p*16, j0 = wid*32;
  __shared__ __align__(16) h16 hs[2][16*HSP];

  if (kind == 0){ // ---- A: h1 recurrence ----
    f16x8 bw[3][2][8];
    for (int gg=0; gg<3; ++gg) for (int jt=0; jt<2; ++jt) for (int kk=0; kk<8; ++kk)
      bw[gg][jt][kk] = ld8(Whh0 + (size_t)(gg*256 + j0 + jt*16 + l15)*256 + kk*32 + lg*8);
    float bhn[2] = { bhh0[512 + j0 + l15], bhh0[512 + j0 + 16 + l15] };
    float h_own[2][4] = {{0,0,0,0},{0,0,0,0}};
    for (int i = tid; i < 16*HSP; i += 512) hs[0][i] = (h16)0.f;
    __syncthreads();
    for (int t = 0; t < 128; ++t){
      const int cur = t & 1, nxt = cur ^ 1;
      int tok[4];
      for (int r=0; r<4; ++r) tok[r] = target[(bg0 + 4*lg + r)*128 + t];
      f32x4 acc[3][2]; float gn[2][4];
      for (int jt=0; jt<2; ++jt){
        int u0 = j0 + jt*16 + l15;
        for (int r=0; r<4; ++r){
          const float* er = emb_all + (size_t)tok[r]*768;
          const float* cr = ctxp + (size_t)(bg0 + 4*lg + r)*768;
          acc[0][jt][r] = er[u0]       + cr[u0];
          acc[1][jt][r] = er[256 + u0] + cr[256 + u0];
          gn[jt][r]     = er[512 + u0] + cr[512 + u0];
          acc[2][jt][r] = bhn[jt];
        }
      }
      f16x8 af[4];
      for (int kk=0; kk<4; ++kk) af[kk] = ld8(&hs[cur][l15*HSP + kk*32 + lg*8]);
      for (int kk=0; kk<4; ++kk) for (int gg=0; gg<3; ++gg) for (int jt=0; jt<2; ++jt)
        acc[gg][jt] = mfma16(af[kk], bw[gg][jt][kk], acc[gg][jt]);
      for (int kk=0; kk<4; ++kk) af[kk] = ld8(&hs[cur][l15*HSP + (kk+4)*32 + lg*8]);
      for (int kk=0; kk<4; ++kk) for (int gg=0; gg<3; ++gg) for (int jt=0; jt<2; ++jt)
        acc[gg][jt] = mfma16(af[kk], bw[gg][jt][kk+4], acc[gg][jt]);
      for (int jt=0; jt<2; ++jt) for (int r=0; r<4; ++r){
        int b = 4*lg + r, j = j0 + jt*16 + l15;
        float rr = sigm(acc[0][jt][r]);
        float zz = sigm(acc[1][jt][r]);
        float nn = tanhx(gn[jt][r] + rr*acc[2][jt][r]);
        float hv = (1.f - zz)*nn + zz*h_own[jt][r];
        h_own[jt][r] = hv;
        h16 hb = (h16)hv;
        h1n[(size_t)(t*32 + bg0 + b)*256 + j] = hb;
        hs[nxt][b*HSP + j] = hb;
      }
      post_flag(&flagA[p*128 + t], tid);
    }
  } else if (kind == 1){ // ---- C: gi2 = h1n @ Wih1^T + d1bias ----
    f16x8 bw[3][2][8];
    for (int gg=0; gg<3; ++gg) for (int jt=0; jt<2; ++jt) for (int kk=0; kk<8; ++kk)
      bw[gg][jt][kk] = ld8(Wih1 + (size_t)(gg*256 + j0 + jt*16 + l15)*256 + kk*32 + lg*8);
    float bi[3][2];
    for (int gg=0; gg<3; ++gg) for (int jt=0; jt<2; ++jt) bi[gg][jt] = d1bias[gg*256 + j0 + jt*16 + l15];
    for (int t = 0; t < 128; ++t){
      waitflag(&flagA[p*128 + t]);
      const h16* hb = h1n + (size_t)(t*32 + bg0)*256;
      f32x4 acc[3][2];
      for (int gg=0; gg<3; ++gg) for (int jt=0; jt<2; ++jt) for (int r=0; r<4; ++r)
        acc[gg][jt][r] = bi[gg][jt];
      f16x8 af[4];
      for (int kk=0; kk<4; ++kk) af[kk] = ld8(hb + l15*256 + kk*32 + lg*8);
      for (int kk=0; kk<4; ++kk) for (int gg=0; gg<3; ++gg) for (int jt=0; jt<2; ++jt)
        acc[gg][jt] = mfma16(af[kk], bw[gg][jt][kk], acc[gg][jt]);
      for (int kk=0; kk<4; ++kk) af[kk] = ld8(hb + l15*256 + (kk+4)*32 + lg*8);
      for (int kk=0; kk<4; ++kk) for (int gg=0; gg<3; ++gg) for (int jt=0; jt<2; ++jt)
        acc[gg][jt] = mfma16(af[kk], bw[gg][jt][kk+4], acc[gg][jt]);
      for (int gg=0; gg<3; ++gg) for (int jt=0; jt<2; ++jt) for (int r=0; r<4; ++r){
        int b = 4*lg + r, u = gg*256 + j0 + jt*16 + l15;
        gi2[(size_t)(t*32 + bg0 + b)*768 + u] = acc[gg][jt][r];
      }
      post_flag(&flagC[p*128 + t], tid);
    }
  } else { // ---- B: h2 recurrence ----
    f16x8 bw[3][2][8];
    for (int gg=0; gg<3; ++gg) for (int jt=0; jt<2; ++jt) for (int kk=0; kk<8; ++kk)
      bw[gg][jt][kk] = ld8(Whh1 + (size_t)(gg*256 + j0 + jt*16 + l15)*256 + kk*32 + lg*8);
    float bhn[2] = { bhh1[512 + j0 + l15], bhh1[512 + j0 + 16 + l15] };
    float h_own[2][4] = {{0,0,0,0},{0,0,0,0}};
    for (int i = tid; i < 16*HSP; i += 512) hs[0][i] = (h16)0.f;
    __syncthreads();
    for (int t = 0; t < 128; ++t){
      const int cur = t & 1, nxt = cur ^ 1;
      f32x4 acc[3][2];
      for (int gg=0; gg<3; ++gg) for (int jt=0; jt<2; ++jt) for (int r=0; r<4; ++r)
        acc[gg][jt][r] = (gg == 2) ? bhn[jt] : 0.f;
      f16x8 af[4];
      for (int kk=0; kk<4; ++kk) af[kk] = ld8(&hs[cur][l15*HSP + kk*32 + lg*8]);
      for (int kk=0; kk<4; ++kk) for (int gg=0; gg<3; ++gg) for (int jt=0; jt<2; ++jt)
        acc[gg][jt] = mfma16(af[kk], bw[gg][jt][kk], acc[gg][jt]);
      for (int kk=0; kk<4; ++kk) af[kk] = ld8(&hs[cur][l15*HSP + (kk+4)*32 + lg*8]);
      for (int kk=0; kk<4; ++kk) for (int gg=0; gg<3; ++gg) for (int jt=0; jt<2; ++jt)
        acc[gg][jt] = mfma16(af[kk], bw[gg][jt][kk+4], acc[gg][jt]);
      waitflag(&flagC[p*128 + t]);
      const float* g2 = gi2 + (size_t)(t*32 + bg0)*768;
      for (int jt=0; jt<2; ++jt) for (int r=0; r<4; ++r){
        int b = 4*lg + r, j = j0 + jt*16 + l15;
        float gr  = g2[(size_t)b*768 + j];
        float gz  = g2[(size_t)b*768 + 256 + j];
        float gnv = g2[(size_t)b*768 + 512 + j];
        float rr = sigm(gr + acc[0][jt][r]);
        float zz = sigm(gz + acc[1][jt][r]);
        float nn = tanhx(gnv + rr*acc[2][jt][r]);
        float hv = (1.f - zz)*nn + zz*h_own[jt][r];
        h_own[jt][r] = hv;
        h16 hb = (h16)hv;
        h2a[(size_t)(t*32 + bg0 + b)*256 + j] = hb;
        hs[nxt][b*HSP + j] = hb;
      }
      __syncthreads();
    }
  }
}

// --------------------------------- host ------------------------------------
extern "C" void kernel_launch(void* const* d_in, const int* in_sizes, int n_in,
                              void* d_out, int out_size, void* d_ws, size_t ws_size,
                              hipStream_t stream){
  const float* source = (const float*)d_in[0];
  const int*   target = (const int*)  d_in[1];
  const float* eWihF = (const float*)d_in[2];
  const float* eWhhF = (const float*)d_in[3];
  const float* eBihF = (const float*)d_in[4];
  const float* eBhhF = (const float*)d_in[5];
  const float* eWihB = (const float*)d_in[6];
  const float* eWhhB = (const float*)d_in[7];
  const float* eBihB = (const float*)d_in[8];
  const float* eBhhB = (const float*)d_in[9];
  const float* attW  = (const float*)d_in[10];
  // d_in[11] = att_b : cancels in softmax, unused
  const float* emb   = (const float*)d_in[12];
  const float* d0Wih = (const float*)d_in[13];
  const float* d0Whh = (const float*)d_in[14];
  const float* d0bih = (const float*)d_in[15];
  const float* d0bhh = (const float*)d_in[16];
  const float* d1Wih = (const float*)d_in[17];
  const float* d1Whh = (const float*)d_in[18];
  const float* d1bih = (const float*)d_in[19];
  const float* d1bhh = (const float*)d_in[20];
  const float* outW  = (const float*)d_in[21];
  const float* outB  = (const float*)d_in[22];

  constexpr size_t OFF_XT   = 0;
  constexpr size_t OFF_GIE  = OFF_XT   + 16384ull*512*2;
  constexpr size_t OFF_ENC  = OFF_GIE  + 16384ull*1536*2;
  constexpr size_t OFF_WIHE = OFF_ENC  + 32ull*512*512*2;
  constexpr size_t OFF_WHHF = OFF_WIHE + 1536ull*512*2;
  constexpr size_t OFF_WHHB = OFF_WHHF + 768ull*256*2;
  constexpr size_t OFF_WHH0 = OFF_WHHB + 768ull*256*2;
  constexpr size_t OFF_WIH1 = OFF_WHH0 + 768ull*256*2;
  constexpr size_t OFF_WHH1 = OFF_WIH1 + 768ull*256*2;
  constexpr size_t OFF_OUTW = OFF_WHH1 + 768ull*256*2;
  constexpr size_t OFF_EMBB = OFF_OUTW + 512ull*256*2;
  constexpr size_t OFF_W0E  = OFF_EMBB + 512ull*128*2;
  constexpr size_t OFF_W0C  = OFF_W0E  + 768ull*128*2;
  constexpr size_t OFF_CTXB = OFF_W0C  + 768ull*512*2;
  constexpr size_t OFF_EMBA = OFF_CTXB + 32ull*512*2;
  constexpr size_t OFF_CTXP = OFF_EMBA + 512ull*768*4;
  constexpr size_t OFF_H1N  = OFF_CTXP + 32ull*768*4;
  constexpr size_t OFF_GI2  = OFF_H1N  + 128ull*32*256*2;
  constexpr size_t OFF_H2A  = OFF_GI2  + 128ull*32*768*4;
  constexpr size_t OFF_EBIA = OFF_H2A  + 128ull*32*256*2;
  constexpr size_t OFF_D0B  = OFF_EBIA + 1536*4;
  constexpr size_t OFF_D1B  = OFF_D0B  + 768*4;
  constexpr size_t OFF_FLG  = OFF_D1B  + 768*4;

  char* ws = (char*)d_ws;
  h16*   Xt      = (h16*)(ws + OFF_XT);
  h16*   gi_enc  = (h16*)(ws + OFF_GIE);
  h16*   ench    = (h16*)(ws + OFF_ENC);
  h16*   WihE    = (h16*)(ws + OFF_WIHE);
  h16*   WhhFh   = (h16*)(ws + OFF_WHHF);
  h16*   WhhBh   = (h16*)(ws + OFF_WHHB);
  h16*   Whh0h   = (h16*)(ws + OFF_WHH0);
  h16*   Wih1h   = (h16*)(ws + OFF_WIH1);
  h16*   Whh1h   = (h16*)(ws + OFF_WHH1);
  h16*   outWh   = (h16*)(ws + OFF_OUTW);
  h16*   embH    = (h16*)(ws + OFF_EMBB);
  h16*   W0E     = (h16*)(ws + OFF_W0E);
  h16*   W0C     = (h16*)(ws + OFF_W0C);
  h16*   ctxH    = (h16*)(ws + OFF_CTXB);
  float* emb_all = (float*)(ws + OFF_EMBA);
  float* ctxp    = (float*)(ws + OFF_CTXP);
  h16*   h1n     = (h16*)(ws + OFF_H1N);
  float* gi2     = (float*)(ws + OFF_GI2);
  h16*   h2a     = (h16*)(ws + OFF_H2A);
  float* ebias   = (float*)(ws + OFF_EBIA);
  float* d0bias  = (float*)(ws + OFF_D0B);
  float* d1bias  = (float*)(ws + OFF_D1B);
  int*   flagA   = (int*)(ws + OFF_FLG);
  int*   flagC   = flagA + 256;

  hipMemsetAsync(ws + OFF_FLG, 0, 2048, stream);
  k_transpose<<<2048, 256, 0, stream>>>(source, Xt);

  CastSegs cs;
  const float* srcs[11] = { eWihF, eWihB, eWhhF, eWhhB, d0Whh, d1Wih, d1Whh, outW, emb, d0Wih, d0Wih + 128 };
  h16* dsts[11] = { WihE, WihE + 768*512, WhhFh, WhhBh, Whh0h, Wih1h, Whh1h, outWh, embH, W0E, W0C };
  int strides[11] = { 512, 512, 256, 256, 256, 256, 256, 256, 128, 640, 640 };
  int lgrs[11]    = { 9,   9,   8,   8,   8,   8,   8,   8,   7,   7,   9 };
  int blks[11]    = { 192, 192, 96,  96,  96,  96,  96,  64,  32,  48,  192 };
  cs.startblk[0] = 0;
  for (int i = 0; i < 11; ++i){
    cs.src[i] = srcs[i]; cs.dst[i] = dsts[i]; cs.sstride[i] = strides[i]; cs.lgr[i] = lgrs[i];
    cs.startblk[i+1] = cs.startblk[i] + blks[i];
  }
  k_cast<<<1200, 256, 0, stream>>>(cs);
  k_bias<<<1, 256, 0, stream>>>(eBihF, eBhhF, eBihB, eBhhB, d0bih, d0bhh, d1bih, d1bhh,
                                ebias, d0bias, d1bias);

  GemmP ge; ge.A = Xt; ge.B = WihE; ge.bias = ebias; ge.Cf = nullptr; ge.Ch = gi_enc; ge.Crm = nullptr;
  ge.M = 16384; ge.N = 1536; ge.K = 512; ge.lda = 512; ge.ldb = 512;
  k_gemm<<<dim3(24, 128), 256, 0, stream>>>(ge);

  k_enc_rnn<<<4, 512, 0, stream>>>(WhhFh, WhhBh, eBhhF, eBhhB, gi_enc, ench);
  k_attn<<<32, 256, 0, stream>>>(ench, attW, ctxH);

  GemmP gc; gc.A = ctxH; gc.B = W0C; gc.bias = nullptr; gc.Cf = ctxp; gc.Ch = nullptr; gc.Crm = nullptr;
  gc.M = 32; gc.N = 768; gc.K = 512; gc.lda = 512; gc.ldb = 512;
  k_gemm<<<dim3(12, 1), 256, 0, stream>>>(gc);

  GemmP gm; gm.A = embH; gm.B = W0E; gm.bias = d0bias; gm.Cf = emb_all; gm.Ch = nullptr; gm.Crm = nullptr;
  gm.M = 512; gm.N = 768; gm.K = 128; gm.lda = 128; gm.ldb = 128;
  k_gemm<<<dim3(12, 4), 256, 0, stream>>>(gm);

  k_dec_rnn<<<6, 512, 0, stream>>>(Whh0h, Wih1h, Whh1h, d0bhh, d1bias, d1bhh,
                                   emb_all, ctxp, target, h1n, gi2, h2a, flagA, flagC);

  GemmP go; go.A = h2a; go.B = outWh; go.bias = outB; go.Cf = nullptr; go.Ch = nullptr; go.Crm = (float*)d_out;
  go.M = 4096; go.N = 512; go.K = 256; go.lda = 256; go.ldb = 256;
  k_gemm<<<dim3(8, 32), 256, 0, stream>>>(go);
}